// Round 8
// baseline (487.672 us; speedup 1.0000x reference)
//
#include <hip/hip_runtime.h>
#include <hip/hip_fp16.h>
#include <hip/hip_cooperative_groups.h>

namespace cg = cooperative_groups;

// ---------------------------------------------------------------------------
// GCN forward: 2-layer, fused normalization.
//   deg[d] = in_degree(d) + 1 (self loop);  dinv = 1/sqrt(deg)
//   g1 = fp16( (x @ W1) .* dinv )           [f16 MFMA, f32 accum]
//   h  = relu(dinv[d] * (sum_{s->d} g1[s] + g1[d]) + b1)
//   g2 = dinv .* (h @ W2)                   (fused into agg1 epilogue)
//   z  = dinv[d] * (sum_{s->d} g2[s] + g2[d]) + b2
//   out = log_softmax(z)
// CSR build fused into ONE cooperative kernel: decode edges once, keep
// (src,dst,ticket) in REGISTERS across grid.sync, scan in-kernel, fill from
// registers. Removes s32/dt staging (13MB), memset, and 5 launches.
// ---------------------------------------------------------------------------

#define DIM 128
#define EPT 4          // edges per thread in the cooperative CSR kernel

typedef _Float16 f16x8 __attribute__((ext_vector_type(8)));
typedef float f32x4 __attribute__((ext_vector_type(4)));

// ---------------------------------------------------------------------------
// Cooperative CSR builder. Grid: nblk*256 threads, nblk >= ntiles, co-resident.
// Phases: zero counts | decode+count+ticket | tile sums | scan tiles (+W1T
// prep on blocks 1..4) | row_ptr+dinv | fill col_idx from registers.
// ---------------------------------------------------------------------------
__global__ void __launch_bounds__(256) csr_coop_kernel(
        const int* __restrict__ ei, const float* __restrict__ W1,
        int* __restrict__ counts, int* __restrict__ tileSums,
        int* __restrict__ row_ptr, float* __restrict__ dinv,
        int* __restrict__ col_idx, __half* __restrict__ W1T,
        int n, int e, int ntiles) {
    cg::grid_group grid = cg::this_grid();
    int t = threadIdx.x;
    int tid = blockIdx.x * 256 + t;
    int NT = gridDim.x * 256;

    __shared__ __half wtile[32 * 136];   // W1 transpose staging (blocks 1..4)
    __shared__ int sred[4];
    __shared__ int sflag;

    // int64-vs-int32 detect (int64 edge_index has zero high words)
    int hv = (t < 32 && (2 * t + 1) < 2 * e) ? ei[2 * t + 1] : 0;
    unsigned long long nz = __ballot(hv != 0);
    if (t == 0) sflag = (nz == 0ULL) ? 1 : 0;

    // phase 0: zero counts
    for (int i = tid; i < n; i += NT) counts[i] = 0;
    __syncthreads();
    int is64 = sflag;
    grid.sync();

    // phase 1: decode + in-degree count + ticket; keep in registers
    int se[EPT], de[EPT], tk[EPT];
    long long base = (long long)tid * EPT;
#pragma unroll
    for (int k = 0; k < EPT; ++k) {
        long long idx = base + k;
        if (idx < e) {
            se[k] = is64 ? (int)((const long long*)ei)[idx] : ei[idx];
            de[k] = is64 ? (int)((const long long*)ei)[e + idx] : ei[e + idx];
            tk[k] = atomicAdd(&counts[de[k]], 1);
        }
    }
    grid.sync();

    // phase 2: per-tile sums (block b -> nodes [b*256, b*256+256))
    if (blockIdx.x < ntiles) {
        int i = blockIdx.x * 256 + t;
        int v = (i < n) ? counts[i] : 0;
        int lane = t & 63;
#pragma unroll
        for (int off = 32; off > 0; off >>= 1) v += __shfl_down(v, off);
        if (lane == 0) sred[t >> 6] = v;
        __syncthreads();
        if (t == 0) tileSums[blockIdx.x] = sred[0] + sred[1] + sred[2] + sred[3];
    }
    grid.sync();

    // phase 3: block 0 exclusive-scans tileSums; blocks 1..4 build W1T f16
    if (blockIdx.x == 0) {
        int v = (t < ntiles) ? tileSums[t] : 0;
        int lane = t & 63, w = t >> 6;
        int x = v;
#pragma unroll
        for (int off = 1; off < 64; off <<= 1) {
            int y = __shfl_up(x, off);
            if (lane >= off) x += y;
        }
        if (lane == 63) sred[w] = x;
        __syncthreads();
        int add = 0;
        for (int k = 0; k < w; ++k) add += sred[k];
        int incl = x + add;
        if (t < ntiles) tileSums[t] = incl - v;          // exclusive
        if (t == ntiles - 1) tileSums[ntiles] = incl;    // grand total
    } else if (blockIdx.x <= 4) {
        int c0 = (blockIdx.x - 1) * 32;   // 32 output cols per block
        for (int it = 0; it < 16; ++it) {
            int k = it * 8 + (t >> 5);
            int c = t & 31;
            wtile[c * 136 + k] = __float2half(W1[(size_t)k * DIM + c0 + c]);
        }
        __syncthreads();
#pragma unroll
        for (int it = 0; it < 2; ++it) {
            int c = t >> 3;
            int kc = (t & 7) + it * 8;
            *(float4*)((char*)(W1T + (size_t)(c0 + c) * DIM) + kc * 16) =
                *(float4*)((char*)(wtile + c * 136) + kc * 16);
        }
    }
    grid.sync();

    // phase 4: row_ptr + dinv
    if (blockIdx.x < ntiles) {
        int i = blockIdx.x * 256 + t;
        int v = (i < n) ? counts[i] : 0;
        int lane = t & 63, w = t >> 6;
        int x = v;
#pragma unroll
        for (int off = 1; off < 64; off <<= 1) {
            int y = __shfl_up(x, off);
            if (lane >= off) x += y;
        }
        if (lane == 63) sred[w] = x;
        __syncthreads();
        int add = tileSums[blockIdx.x];
        for (int k = 0; k < w; ++k) add += sred[k];
        if (i < n) {
            row_ptr[i] = add + x - v;
            dinv[i] = rsqrtf((float)(v + 1));
        }
        if (i == n - 1) row_ptr[n] = add + x;
    }
    grid.sync();

    // phase 5: fill col_idx straight from registers (no re-decode, no atomics)
#pragma unroll
    for (int k = 0; k < EPT; ++k) {
        long long idx = base + k;
        if (idx < e) col_idx[row_ptr[de[k]] + tk[k]] = se[k];
    }
}

// ---------------------------------------------------------------------------
// gemm1 (MFMA): 128 rows x 128 cols per block, 4 waves, wave owns 32 rows.
// xs: x tile as f16, XOR-swizzled; wt: W1T [col][k] f16, same swizzle.
// A/B frag: outer=lane&15, k=(lane>>4)*8+j. C/D: col=lane&15, row=(lane>>4)*4+reg.
// ---------------------------------------------------------------------------
#define GR 128
__global__ __launch_bounds__(256) void gemm1_kernel(
        const float* __restrict__ x, const __half* __restrict__ W1T,
        const float* __restrict__ dinv, __half* __restrict__ g1, int n) {
    __shared__ short xs[GR * DIM];    // 32 KB
    __shared__ short wt[DIM * DIM];   // 32 KB
    int t = threadIdx.x;
    int row0 = blockIdx.x * GR;

    // stage W1T (f16 [col][k]): 2048 x 16B, swizzled write
#pragma unroll
    for (int i = 0; i < 8; ++i) {
        int f = t + i * 256;
        int col = f >> 4, kc = f & 15;
        unsigned int byte = (unsigned)(col * 256 + kc * 16);
        byte ^= (unsigned)((col & 7) << 4);
        *(float4*)((char*)wt + byte) = *(const float4*)((const char*)W1T + (size_t)f * 16);
    }
    // stage x tile f32 -> f16: 8B swizzled writes
#pragma unroll
    for (int i = 0; i < 16; ++i) {
        int f = t + i * 256;
        int r = f >> 5, c4 = f & 31;
        float4 v = make_float4(0.f, 0.f, 0.f, 0.f);
        if (row0 + r < n)
            v = *(const float4*)(x + (size_t)(row0 + r) * DIM + c4 * 4);
        __half2 p01 = __floats2half2_rn(v.x, v.y);
        __half2 p23 = __floats2half2_rn(v.z, v.w);
        float2 pk;
        ((__half2*)&pk)[0] = p01;
        ((__half2*)&pk)[1] = p23;
        unsigned int byte = (unsigned)(r * 256 + c4 * 8);
        byte ^= (unsigned)((r & 7) << 4);
        *(float2*)((char*)xs + byte) = pk;
    }
    __syncthreads();

    int w  = t >> 6;     // wave 0..3 -> rows w*32 .. w*32+31
    int l  = t & 63;
    int lr = l & 15;     // A row / B col within fragment
    int lg = l >> 4;     // k-group (8 contiguous k each)

    f32x4 acc[2][8];
#pragma unroll
    for (int m = 0; m < 2; ++m)
#pragma unroll
        for (int cf = 0; cf < 8; ++cf) acc[m][cf] = (f32x4){0.f, 0.f, 0.f, 0.f};

#pragma unroll
    for (int kt = 0; kt < 4; ++kt) {
        int kByte = kt * 64 + lg * 16;
        f16x8 a[2];
#pragma unroll
        for (int m = 0; m < 2; ++m) {
            int row = w * 32 + m * 16 + lr;
            unsigned int byte = (unsigned)(row * 256 + kByte);
            byte ^= (unsigned)((row & 7) << 4);
            a[m] = *(const f16x8*)((const char*)xs + byte);
        }
#pragma unroll
        for (int cf = 0; cf < 8; ++cf) {
            int col = cf * 16 + lr;
            unsigned int byte = (unsigned)(col * 256 + kByte);
            byte ^= (unsigned)((col & 7) << 4);
            f16x8 b = *(const f16x8*)((const char*)wt + byte);
            acc[0][cf] = __builtin_amdgcn_mfma_f32_16x16x32_f16(a[0], b, acc[0][cf], 0, 0, 0);
            acc[1][cf] = __builtin_amdgcn_mfma_f32_16x16x32_f16(a[1], b, acc[1][cf], 0, 0, 0);
        }
    }

    // epilogue: C/D frag row=(l>>4)*4+reg, col=lane&15
#pragma unroll
    for (int m = 0; m < 2; ++m)
#pragma unroll
        for (int r4 = 0; r4 < 4; ++r4) {
            int row = row0 + w * 32 + m * 16 + lg * 4 + r4;
            if (row < n) {
                float dv = dinv[row];
#pragma unroll
                for (int cf = 0; cf < 8; ++cf) {
                    int col = cf * 16 + lr;
                    g1[(size_t)row * DIM + col] = __float2half(acc[m][cf][r4] * dv);
                }
            }
        }
}

// One WAVE per dst node, lane owns 2 features (half2 = 4B; 256B/edge wave-wide).
// row_ptr/col_idx reads are wave-uniform -> scalarized. 8 edges in flight.
__global__ void agg1_kernel(const __half* __restrict__ g1, const int* __restrict__ row_ptr,
                            const int* __restrict__ col_idx, const float* __restrict__ dinv,
                            const float* __restrict__ b1, const float* __restrict__ W2,
                            float* __restrict__ g2, int n) {
    int lane = threadIdx.x & 63;
    int wid  = threadIdx.x >> 6;              // 0..3
    int d = blockIdx.x * 4 + wid;
    if (d >= n) return;
    const __half2* base = (const __half2*)g1 + lane;   // [n][64] half2
    float2 vf = __half22float2(base[d * 64]);          // self loop
    float acc0 = vf.x, acc1 = vf.y;
    int beg = __builtin_amdgcn_readfirstlane(row_ptr[d]);
    int end = __builtin_amdgcn_readfirstlane(row_ptr[d + 1]);
    int j = beg;
    for (; j + 8 <= end; j += 8) {
        int s0 = col_idx[j + 0], s1 = col_idx[j + 1];
        int s2 = col_idx[j + 2], s3 = col_idx[j + 3];
        int s4 = col_idx[j + 4], s5 = col_idx[j + 5];
        int s6 = col_idx[j + 6], s7 = col_idx[j + 7];
        __half2 h0 = base[s0 * 64], h1 = base[s1 * 64];
        __half2 h2 = base[s2 * 64], h3 = base[s3 * 64];
        __half2 h4 = base[s4 * 64], h5 = base[s5 * 64];
        __half2 h6 = base[s6 * 64], h7 = base[s7 * 64];
        float2 u0 = __half22float2(h0), u1 = __half22float2(h1);
        float2 u2 = __half22float2(h2), u3 = __half22float2(h3);
        float2 u4 = __half22float2(h4), u5 = __half22float2(h5);
        float2 u6 = __half22float2(h6), u7 = __half22float2(h7);
        acc0 += ((u0.x + u1.x) + (u2.x + u3.x)) + ((u4.x + u5.x) + (u6.x + u7.x));
        acc1 += ((u0.y + u1.y) + (u2.y + u3.y)) + ((u4.y + u5.y) + (u6.y + u7.y));
    }
    for (; j < end; ++j) {
        float2 u = __half22float2(base[col_idx[j] * 64]);
        acc0 += u.x; acc1 += u.y;
    }
    float dv = dinv[d];
    int f0 = lane * 2, f1 = f0 + 1;
    float h0 = fmaxf(dv * acc0 + b1[f0], 0.f);
    float h1 = fmaxf(dv * acc1 + b1[f1], 0.f);
    float z0 = fmaf(h1, W2[f1 * 2 + 0], h0 * W2[f0 * 2 + 0]);
    float z1 = fmaf(h1, W2[f1 * 2 + 1], h0 * W2[f0 * 2 + 1]);
#pragma unroll
    for (int off = 32; off > 0; off >>= 1) {
        z0 += __shfl_down(z0, off);
        z1 += __shfl_down(z1, off);
    }
    if (lane == 0) {
        g2[d * 2 + 0] = dv * z0;
        g2[d * 2 + 1] = dv * z1;
    }
}

// Quarter-wave (16 lanes) per dst node: lane-per-edge gather, 16-wide shuffle
// reduce, bias + log_softmax on sub-lane 0. (avg degree ~16 -> 64-lane waves
// left 48 lanes idle)
__global__ void agg2_kernel(const float* __restrict__ g2, const int* __restrict__ row_ptr,
                            const int* __restrict__ col_idx, const float* __restrict__ dinv,
                            const float* __restrict__ b2, float* __restrict__ out, int n) {
    int t = threadIdx.x;
    int sub = t & 15;
    int d = blockIdx.x * 16 + (t >> 4);
    if (d >= n) return;
    int beg = row_ptr[d], end = row_ptr[d + 1];
    float a0 = 0.f, a1 = 0.f;
    const float2* g2v = (const float2*)g2;
    for (int j = beg + sub; j < end; j += 16) {
        float2 v = g2v[col_idx[j]];
        a0 += v.x; a1 += v.y;
    }
#pragma unroll
    for (int off = 8; off > 0; off >>= 1) {
        a0 += __shfl_down(a0, off, 16);
        a1 += __shfl_down(a1, off, 16);
    }
    if (sub == 0) {
        float2 self = g2v[d];
        float dv = dinv[d];
        float z0 = dv * (a0 + self.x) + b2[0];
        float z1 = dv * (a1 + self.y) + b2[1];
        float m = fmaxf(z0, z1);
        float l = m + logf(expf(z0 - m) + expf(z1 - m));
        out[d * 2 + 0] = z0 - l;
        out[d * 2 + 1] = z1 - l;
    }
}

extern "C" void kernel_launch(void* const* d_in, const int* in_sizes, int n_in,
                              void* d_out, int out_size, void* d_ws, size_t ws_size,
                              hipStream_t stream) {
    const float* x  = (const float*)d_in[0];
    const int*   ei = (const int*)d_in[1];
    const float* W1 = (const float*)d_in[2];
    const float* b1 = (const float*)d_in[3];
    const float* W2 = (const float*)d_in[4];
    const float* b2 = (const float*)d_in[5];
    float* out = (float*)d_out;

    int n = in_sizes[0] / DIM;   // 50000
    int e = in_sizes[1] / 2;     // 800000
    int ntiles = (n + 255) / 256;                    // 196

    char* wsp = (char*)d_ws;
    size_t used = 0;
    auto alloc = [&](size_t bytes) {
        char* p = wsp + used;
        used += (bytes + 255) & ~(size_t)255;
        return p;
    };
    int*    counts   = (int*)alloc((size_t)n * 4);
    int*    row_ptr  = (int*)alloc((size_t)(n + 1) * 4);
    int*    tileSums = (int*)alloc((size_t)(ntiles + 1) * 4);
    float*  dinv     = (float*)alloc((size_t)n * 4);
    int*    col_idx  = (int*)alloc((size_t)e * 4);
    __half* g1       = (__half*)alloc((size_t)n * DIM * 2);
    float*  g2       = (float*)alloc((size_t)n * 2 * 4);
    __half* W1T      = (__half*)alloc((size_t)DIM * DIM * 2);

    int nblk = (e + 256 * EPT - 1) / (256 * EPT);    // 782 @ e=800k
    if (nblk < ntiles) nblk = ntiles;
    if (nblk < 5) nblk = 5;                          // W1T prep needs blocks 1..4

    void* args[] = {(void*)&ei, (void*)&W1, (void*)&counts, (void*)&tileSums,
                    (void*)&row_ptr, (void*)&dinv, (void*)&col_idx, (void*)&W1T,
                    (void*)&n, (void*)&e, (void*)&ntiles};
    hipLaunchCooperativeKernel((const void*)csr_coop_kernel, dim3(nblk), dim3(256),
                               args, 0, stream);

    gemm1_kernel<<<(n + GR - 1) / GR, 256, 0, stream>>>(x, W1T, dinv, g1, n);
    agg1_kernel<<<(n + 3) / 4, 256, 0, stream>>>(g1, row_ptr, col_idx, dinv, b1, W2, g2, n);
    agg2_kernel<<<(n + 15) / 16, 256, 0, stream>>>(g2, row_ptr, col_idx, dinv, b2, out, n);
}

// Round 9
// 126.700 us; speedup vs baseline: 3.8490x; 3.8490x over previous
//
#include <hip/hip_runtime.h>
#include <hip/hip_fp16.h>

// ---------------------------------------------------------------------------
// GCN forward: 2-layer, fused normalization.
//   deg[d] = in_degree(d) + 1 (self loop);  dinv = rsqrt(deg)
//   g1 = fp16( x @ W1 )                      [f16 MFMA; dinv applied at use]
//   h  = relu(dinv[d] * (sum_{s->d} dinv[s]*g1[s] + dinv[d]*g1[d]) + b1)
//   g2 = dinv .* (h @ W2)                    (fused into agg1 epilogue)
//   z  = dinv[d] * (sum_{s->d} g2[s] + g2[d]) + b2
//   out = log_softmax(z)
// Graph structure as padded ELL (width 64): one atomic pass writes
// col_ell[d*64 + ticket] directly -- no scan, no fill pass, no staging.
// Overflow edges (deg>64; impossible for Poisson(16) input but kept for
// correctness) go to a spill list scanned by the agg kernels (0 entries ->
// one scalar load). Round-8 coop-kernel grid.sync (410us, cross-XCD cache
// flush per sync) reverted.
// ---------------------------------------------------------------------------

#define DIM 128
#define ELLW 64

typedef _Float16 f16x8 __attribute__((ext_vector_type(8)));
typedef float f32x4 __attribute__((ext_vector_type(4)));

// Per-block int64-vs-int32 detection: int64 edge_index has zero high words.
__device__ __forceinline__ int detect_is64(const int* __restrict__ ei, int e) {
    __shared__ int sflag;
    int t = threadIdx.x;
    int hv = (t < 32 && (2 * t + 1) < 2 * e) ? ei[2 * t + 1] : 0;
    unsigned long long nz = __ballot(hv != 0);
    if (t == 0) sflag = (nz == 0ULL) ? 1 : 0;
    __syncthreads();
    return sflag;
}

__device__ __forceinline__ int load_idx(const int* ei, long long pos, int is64) {
    if (is64) return (int)((const long long*)ei)[pos];
    return ei[pos];
}

// Decode + in-degree count + direct ELL scatter (ticket = slot).
// counts[n] is the spill counter (counts array allocated n+64 ints, zeroed).
__global__ void count_ell_kernel(const int* __restrict__ ei, int* __restrict__ counts,
                                 int* __restrict__ col_ell, int2* __restrict__ spill,
                                 int n, int e) {
    int is64 = detect_is64(ei, e);
    int i = blockIdx.x * blockDim.x + threadIdx.x;
    if (i >= e) return;
    int s = load_idx(ei, i, is64);
    int d = load_idx(ei, (long long)e + i, is64);
    int tk = atomicAdd(&counts[d], 1);
    if (tk < ELLW) {
        col_ell[(size_t)d * ELLW + tk] = s;
    } else {
        int p = atomicAdd(&counts[n], 1);
        spill[p] = make_int2(s, d);
    }
}

// W1T[col][k] = f16(W1[k][col]); 4 blocks x 32 cols.
__global__ void w1prep_kernel(const float* __restrict__ W1, __half* __restrict__ W1T) {
    __shared__ __half wtile[32 * 136];
    int t = threadIdx.x;
    int c0 = blockIdx.x * 32;
    for (int it = 0; it < 16; ++it) {
        int k = it * 8 + (t >> 5);
        int c = t & 31;
        wtile[c * 136 + k] = __float2half(W1[(size_t)k * DIM + c0 + c]);
    }
    __syncthreads();
#pragma unroll
    for (int it = 0; it < 2; ++it) {
        int c = t >> 3;
        int kc = (t & 7) + it * 8;
        *(float4*)((char*)(W1T + (size_t)(c0 + c) * DIM) + kc * 16) =
            *(float4*)((char*)(wtile + c * 136) + kc * 16);
    }
}

// ---------------------------------------------------------------------------
// gemm1 (MFMA): g1 = f16(x @ W1). 128 rows x 128 cols per block, 4 waves.
// xs/wt XOR-swizzled ((row&7)<<4). A/B frag outer=lane&15, k=(lane>>4)*8+j;
// C/D col=lane&15, row=(lane>>4)*4+reg.
// ---------------------------------------------------------------------------
#define GR 128
__global__ __launch_bounds__(256) void gemm1_kernel(
        const float* __restrict__ x, const __half* __restrict__ W1T,
        __half* __restrict__ g1, int n) {
    __shared__ short xs[GR * DIM];    // 32 KB
    __shared__ short wt[DIM * DIM];   // 32 KB
    int t = threadIdx.x;
    int row0 = blockIdx.x * GR;

#pragma unroll
    for (int i = 0; i < 8; ++i) {
        int f = t + i * 256;
        int col = f >> 4, kc = f & 15;
        unsigned int byte = (unsigned)(col * 256 + kc * 16);
        byte ^= (unsigned)((col & 7) << 4);
        *(float4*)((char*)wt + byte) = *(const float4*)((const char*)W1T + (size_t)f * 16);
    }
#pragma unroll
    for (int i = 0; i < 16; ++i) {
        int f = t + i * 256;
        int r = f >> 5, c4 = f & 31;
        float4 v = make_float4(0.f, 0.f, 0.f, 0.f);
        if (row0 + r < n)
            v = *(const float4*)(x + (size_t)(row0 + r) * DIM + c4 * 4);
        __half2 p01 = __floats2half2_rn(v.x, v.y);
        __half2 p23 = __floats2half2_rn(v.z, v.w);
        float2 pk;
        ((__half2*)&pk)[0] = p01;
        ((__half2*)&pk)[1] = p23;
        unsigned int byte = (unsigned)(r * 256 + c4 * 8);
        byte ^= (unsigned)((r & 7) << 4);
        *(float2*)((char*)xs + byte) = pk;
    }
    __syncthreads();

    int w  = t >> 6;
    int l  = t & 63;
    int lr = l & 15;
    int lg = l >> 4;

    f32x4 acc[2][8];
#pragma unroll
    for (int m = 0; m < 2; ++m)
#pragma unroll
        for (int cf = 0; cf < 8; ++cf) acc[m][cf] = (f32x4){0.f, 0.f, 0.f, 0.f};

#pragma unroll
    for (int kt = 0; kt < 4; ++kt) {
        int kByte = kt * 64 + lg * 16;
        f16x8 a[2];
#pragma unroll
        for (int m = 0; m < 2; ++m) {
            int row = w * 32 + m * 16 + lr;
            unsigned int byte = (unsigned)(row * 256 + kByte);
            byte ^= (unsigned)((row & 7) << 4);
            a[m] = *(const f16x8*)((const char*)xs + byte);
        }
#pragma unroll
        for (int cf = 0; cf < 8; ++cf) {
            int col = cf * 16 + lr;
            unsigned int byte = (unsigned)(col * 256 + kByte);
            byte ^= (unsigned)((col & 7) << 4);
            f16x8 b = *(const f16x8*)((const char*)wt + byte);
            acc[0][cf] = __builtin_amdgcn_mfma_f32_16x16x32_f16(a[0], b, acc[0][cf], 0, 0, 0);
            acc[1][cf] = __builtin_amdgcn_mfma_f32_16x16x32_f16(a[1], b, acc[1][cf], 0, 0, 0);
        }
    }

#pragma unroll
    for (int m = 0; m < 2; ++m)
#pragma unroll
        for (int r4 = 0; r4 < 4; ++r4) {
            int row = row0 + w * 32 + m * 16 + lg * 4 + r4;
            if (row < n) {
#pragma unroll
                for (int cf = 0; cf < 8; ++cf) {
                    int col = cf * 16 + lr;
                    g1[(size_t)row * DIM + col] = __float2half(acc[m][cf][r4]);
                }
            }
        }
}

// One WAVE per dst node, lane owns 2 features. ELL row + counts reads are
// wave-uniform -> scalarized. dinv recomputed as rsqrt(counts+1) (cheap).
// 8 edges in flight, per-edge dinv[s] applied via fmaf.
__global__ void agg1_kernel(const __half* __restrict__ g1, const int* __restrict__ counts,
                            const int* __restrict__ col_ell, const int2* __restrict__ spill,
                            const float* __restrict__ b1, const float* __restrict__ W2,
                            float* __restrict__ g2, int n) {
    int lane = threadIdx.x & 63;
    int wid  = threadIdx.x >> 6;
    int d = blockIdx.x * 4 + wid;
    if (d >= n) return;
    int deg = __builtin_amdgcn_readfirstlane(counts[d]);
    float dv = rsqrtf((float)(deg + 1));
    const __half2* base = (const __half2*)g1 + lane;   // [n][64] half2
    float2 vf = __half22float2(base[(size_t)d * 64]);  // self loop (dinv[d])
    float acc0 = dv * vf.x, acc1 = dv * vf.y;
    const int* row = col_ell + (size_t)d * ELLW;
    int m = deg < ELLW ? deg : ELLW;
    int j = 0;
    for (; j + 8 <= m; j += 8) {
        int s0 = row[j + 0], s1 = row[j + 1], s2 = row[j + 2], s3 = row[j + 3];
        int s4 = row[j + 4], s5 = row[j + 5], s6 = row[j + 6], s7 = row[j + 7];
        float w0 = rsqrtf((float)(counts[s0] + 1)), w1 = rsqrtf((float)(counts[s1] + 1));
        float w2 = rsqrtf((float)(counts[s2] + 1)), w3 = rsqrtf((float)(counts[s3] + 1));
        float w4 = rsqrtf((float)(counts[s4] + 1)), w5 = rsqrtf((float)(counts[s5] + 1));
        float w6 = rsqrtf((float)(counts[s6] + 1)), w7 = rsqrtf((float)(counts[s7] + 1));
        __half2 h0 = base[(size_t)s0 * 64], h1 = base[(size_t)s1 * 64];
        __half2 h2 = base[(size_t)s2 * 64], h3 = base[(size_t)s3 * 64];
        __half2 h4 = base[(size_t)s4 * 64], h5 = base[(size_t)s5 * 64];
        __half2 h6 = base[(size_t)s6 * 64], h7 = base[(size_t)s7 * 64];
        float2 u0 = __half22float2(h0), u1 = __half22float2(h1);
        float2 u2 = __half22float2(h2), u3 = __half22float2(h3);
        float2 u4 = __half22float2(h4), u5 = __half22float2(h5);
        float2 u6 = __half22float2(h6), u7 = __half22float2(h7);
        acc0 = fmaf(w0, u0.x, fmaf(w1, u1.x, fmaf(w2, u2.x, fmaf(w3, u3.x, acc0))));
        acc0 = fmaf(w4, u4.x, fmaf(w5, u5.x, fmaf(w6, u6.x, fmaf(w7, u7.x, acc0))));
        acc1 = fmaf(w0, u0.y, fmaf(w1, u1.y, fmaf(w2, u2.y, fmaf(w3, u3.y, acc1))));
        acc1 = fmaf(w4, u4.y, fmaf(w5, u5.y, fmaf(w6, u6.y, fmaf(w7, u7.y, acc1))));
    }
    for (; j < m; ++j) {
        int s = row[j];
        float ws = rsqrtf((float)(counts[s] + 1));
        float2 u = __half22float2(base[(size_t)s * 64]);
        acc0 = fmaf(ws, u.x, acc0);
        acc1 = fmaf(ws, u.y, acc1);
    }
    int sc = __builtin_amdgcn_readfirstlane(counts[n]);   // spill count (normally 0)
    if (sc > 0) {
        for (int i = 0; i < sc; ++i) {
            int2 sp = spill[i];
            if (sp.y == d) {
                float ws = rsqrtf((float)(counts[sp.x] + 1));
                float2 u = __half22float2(base[(size_t)sp.x * 64]);
                acc0 = fmaf(ws, u.x, acc0);
                acc1 = fmaf(ws, u.y, acc1);
            }
        }
    }
    int f0 = lane * 2, f1 = f0 + 1;
    float h0 = fmaxf(dv * acc0 + b1[f0], 0.f);
    float h1 = fmaxf(dv * acc1 + b1[f1], 0.f);
    float z0 = fmaf(h1, W2[f1 * 2 + 0], h0 * W2[f0 * 2 + 0]);
    float z1 = fmaf(h1, W2[f1 * 2 + 1], h0 * W2[f0 * 2 + 1]);
#pragma unroll
    for (int off = 32; off > 0; off >>= 1) {
        z0 += __shfl_down(z0, off);
        z1 += __shfl_down(z1, off);
    }
    if (lane == 0) {
        g2[d * 2 + 0] = dv * z0;
        g2[d * 2 + 1] = dv * z1;
    }
}

// Quarter-wave (16 lanes) per dst node: lane-per-edge ELL gather, 16-wide
// shuffle reduce, bias + log_softmax on sub-lane 0.
__global__ void agg2_kernel(const float* __restrict__ g2, const int* __restrict__ counts,
                            const int* __restrict__ col_ell, const int2* __restrict__ spill,
                            const float* __restrict__ b2, float* __restrict__ out, int n) {
    int t = threadIdx.x;
    int sub = t & 15;
    int d = blockIdx.x * 16 + (t >> 4);
    if (d >= n) return;
    int deg = counts[d];
    int m = deg < ELLW ? deg : ELLW;
    const int* row = col_ell + (size_t)d * ELLW;
    float a0 = 0.f, a1 = 0.f;
    const float2* g2v = (const float2*)g2;
    for (int j = sub; j < m; j += 16) {
        float2 v = g2v[row[j]];
        a0 += v.x; a1 += v.y;
    }
    int sc = counts[n];
    if (sc > 0 && sub == 0) {
        for (int i = 0; i < sc; ++i) {
            int2 sp = spill[i];
            if (sp.y == d) { float2 v = g2v[sp.x]; a0 += v.x; a1 += v.y; }
        }
    }
#pragma unroll
    for (int off = 8; off > 0; off >>= 1) {
        a0 += __shfl_down(a0, off, 16);
        a1 += __shfl_down(a1, off, 16);
    }
    if (sub == 0) {
        float2 self = g2v[d];
        float dv = rsqrtf((float)(deg + 1));
        float z0 = dv * (a0 + self.x) + b2[0];
        float z1 = dv * (a1 + self.y) + b2[1];
        float mm = fmaxf(z0, z1);
        float l = mm + logf(expf(z0 - mm) + expf(z1 - mm));
        out[d * 2 + 0] = z0 - l;
        out[d * 2 + 1] = z1 - l;
    }
}

extern "C" void kernel_launch(void* const* d_in, const int* in_sizes, int n_in,
                              void* d_out, int out_size, void* d_ws, size_t ws_size,
                              hipStream_t stream) {
    const float* x  = (const float*)d_in[0];
    const int*   ei = (const int*)d_in[1];
    const float* W1 = (const float*)d_in[2];
    const float* b1 = (const float*)d_in[3];
    const float* W2 = (const float*)d_in[4];
    const float* b2 = (const float*)d_in[5];
    float* out = (float*)d_out;

    int n = in_sizes[0] / DIM;   // 50000
    int e = in_sizes[1] / 2;     // 800000

    char* wsp = (char*)d_ws;
    size_t used = 0;
    auto alloc = [&](size_t bytes) {
        char* p = wsp + used;
        used += (bytes + 255) & ~(size_t)255;
        return p;
    };
    int*    counts  = (int*)alloc((size_t)(n + 64) * 4);   // [n] = spill counter
    int*    col_ell = (int*)alloc((size_t)n * ELLW * 4);   // 12.8 MB
    int2*   spill   = (int2*)alloc((size_t)e * 8);         // overflow edges
    __half* g1      = (__half*)alloc((size_t)n * DIM * 2);
    float*  g2      = (float*)alloc((size_t)n * 2 * 4);
    __half* W1T     = (__half*)alloc((size_t)DIM * DIM * 2);

    const int tb = 256;
    hipMemsetAsync(counts, 0, (size_t)(n + 64) * 4, stream);
    w1prep_kernel<<<4, 256, 0, stream>>>(W1, W1T);
    gemm1_kernel<<<(n + GR - 1) / GR, 256, 0, stream>>>(x, W1T, g1, n);
    count_ell_kernel<<<(e + tb - 1) / tb, tb, 0, stream>>>(ei, counts, col_ell, spill, n, e);
    agg1_kernel<<<(n + 3) / 4, 256, 0, stream>>>(g1, counts, col_ell, spill, b1, W2, g2, n);
    agg2_kernel<<<(n + 15) / 16, 256, 0, stream>>>(g2, counts, col_ell, spill, b2, out, n);
}

// Round 10
// 122.767 us; speedup vs baseline: 3.9723x; 1.0320x over previous
//
#include <hip/hip_runtime.h>
#include <hip/hip_fp16.h>

// ---------------------------------------------------------------------------
// GCN forward: 2-layer, fused normalization.
//   deg[d] = in_degree(d) + 1 (self loop);  dinv = rsqrt(deg)
//   g1 = fp16( x @ W1 )                      [f16 MFMA; dinv applied at use]
//   h  = relu(dinv[d] * (sum_{s->d} dinv[s]*g1[s] + dinv[d]*g1[d]) + b1)
//   g2 = dinv .* (h @ W2)                    (fused into agg1 epilogue)
//   z  = dinv[d] * (sum_{s->d} g2[s] + g2[d]) + b2
//   out = log_softmax(z)
// Graph structure as padded ELL (width 32, spill list for deg>32).
// Round-9 lesson: one-pass ELL scatter from all XCDs caused 48MB write-amp
// (each XCD's non-coherent L2 dirties its own copy of shared lines).
// Fix: XCD-class partition -- class = (d>>4)&7, block class = blockIdx&7,
// 8 class-replicas per edge chunk. Every counts/col_ell line is written by
// exactly one XCD class; reads go x8 (coalesced, cheap), writes drop ~6x.
// ---------------------------------------------------------------------------

#define DIM 128
#define ELLW 32
#define EPC 4          // edges per thread per class-block

typedef _Float16 f16x8 __attribute__((ext_vector_type(8)));
typedef float f32x4 __attribute__((ext_vector_type(4)));

// Per-block int64-vs-int32 detection: int64 edge_index has zero high words.
__device__ __forceinline__ int detect_is64(const int* __restrict__ ei, int e) {
    __shared__ int sflag;
    int t = threadIdx.x;
    int hv = (t < 32 && (2 * t + 1) < 2 * e) ? ei[2 * t + 1] : 0;
    unsigned long long nz = __ballot(hv != 0);
    if (t == 0) sflag = (nz == 0ULL) ? 1 : 0;
    __syncthreads();
    return sflag;
}

__device__ __forceinline__ int load_idx(const int* ei, long long pos, int is64) {
    if (is64) return (int)((const long long*)ei)[pos];
    return ei[pos];
}

// XCD-class-partitioned decode + count + ELL scatter.
// blockIdx&7 = class; block processes only edges with ((d>>4)&7)==class.
// counts[n] is the spill counter.
__global__ void count_ell_kernel(const int* __restrict__ ei, int* __restrict__ counts,
                                 int* __restrict__ col_ell, int2* __restrict__ spill,
                                 int n, int e) {
    int is64 = detect_is64(ei, e);
    int cls = blockIdx.x & 7;
    long long chunk = blockIdx.x >> 3;
    long long base = chunk * (256 * EPC) + threadIdx.x;
#pragma unroll
    for (int k = 0; k < EPC; ++k) {
        long long i = base + (long long)k * 256;
        if (i < e) {
            int d = load_idx(ei, (long long)e + i, is64);
            if (((d >> 4) & 7) == cls) {
                int s = load_idx(ei, i, is64);
                int tk = atomicAdd(&counts[d], 1);
                if (tk < ELLW) {
                    col_ell[(size_t)d * ELLW + tk] = s;
                } else {
                    int p = atomicAdd(&counts[n], 1);
                    spill[p] = make_int2(s, d);
                }
            }
        }
    }
}

// W1T[col][k] = f16(W1[k][col]); 4 blocks x 32 cols.
__global__ void w1prep_kernel(const float* __restrict__ W1, __half* __restrict__ W1T) {
    __shared__ __half wtile[32 * 136];
    int t = threadIdx.x;
    int c0 = blockIdx.x * 32;
    for (int it = 0; it < 16; ++it) {
        int k = it * 8 + (t >> 5);
        int c = t & 31;
        wtile[c * 136 + k] = __float2half(W1[(size_t)k * DIM + c0 + c]);
    }
    __syncthreads();
#pragma unroll
    for (int it = 0; it < 2; ++it) {
        int c = t >> 3;
        int kc = (t & 7) + it * 8;
        *(float4*)((char*)(W1T + (size_t)(c0 + c) * DIM) + kc * 16) =
            *(float4*)((char*)(wtile + c * 136) + kc * 16);
    }
}

// ---------------------------------------------------------------------------
// gemm1 (MFMA): g1 = f16(x @ W1). 128 rows x 128 cols per block, 4 waves.
// xs/wt XOR-swizzled ((row&7)<<4). A/B frag outer=lane&15, k=(lane>>4)*8+j;
// C/D col=lane&15, row=(lane>>4)*4+reg.
// ---------------------------------------------------------------------------
#define GR 128
__global__ __launch_bounds__(256) void gemm1_kernel(
        const float* __restrict__ x, const __half* __restrict__ W1T,
        __half* __restrict__ g1, int n) {
    __shared__ short xs[GR * DIM];    // 32 KB
    __shared__ short wt[DIM * DIM];   // 32 KB
    int t = threadIdx.x;
    int row0 = blockIdx.x * GR;

#pragma unroll
    for (int i = 0; i < 8; ++i) {
        int f = t + i * 256;
        int col = f >> 4, kc = f & 15;
        unsigned int byte = (unsigned)(col * 256 + kc * 16);
        byte ^= (unsigned)((col & 7) << 4);
        *(float4*)((char*)wt + byte) = *(const float4*)((const char*)W1T + (size_t)f * 16);
    }
#pragma unroll
    for (int i = 0; i < 16; ++i) {
        int f = t + i * 256;
        int r = f >> 5, c4 = f & 31;
        float4 v = make_float4(0.f, 0.f, 0.f, 0.f);
        if (row0 + r < n)
            v = *(const float4*)(x + (size_t)(row0 + r) * DIM + c4 * 4);
        __half2 p01 = __floats2half2_rn(v.x, v.y);
        __half2 p23 = __floats2half2_rn(v.z, v.w);
        float2 pk;
        ((__half2*)&pk)[0] = p01;
        ((__half2*)&pk)[1] = p23;
        unsigned int byte = (unsigned)(r * 256 + c4 * 8);
        byte ^= (unsigned)((r & 7) << 4);
        *(float2*)((char*)xs + byte) = pk;
    }
    __syncthreads();

    int w  = t >> 6;
    int l  = t & 63;
    int lr = l & 15;
    int lg = l >> 4;

    f32x4 acc[2][8];
#pragma unroll
    for (int m = 0; m < 2; ++m)
#pragma unroll
        for (int cf = 0; cf < 8; ++cf) acc[m][cf] = (f32x4){0.f, 0.f, 0.f, 0.f};

#pragma unroll
    for (int kt = 0; kt < 4; ++kt) {
        int kByte = kt * 64 + lg * 16;
        f16x8 a[2];
#pragma unroll
        for (int m = 0; m < 2; ++m) {
            int row = w * 32 + m * 16 + lr;
            unsigned int byte = (unsigned)(row * 256 + kByte);
            byte ^= (unsigned)((row & 7) << 4);
            a[m] = *(const f16x8*)((const char*)xs + byte);
        }
#pragma unroll
        for (int cf = 0; cf < 8; ++cf) {
            int col = cf * 16 + lr;
            unsigned int byte = (unsigned)(col * 256 + kByte);
            byte ^= (unsigned)((col & 7) << 4);
            f16x8 b = *(const f16x8*)((const char*)wt + byte);
            acc[0][cf] = __builtin_amdgcn_mfma_f32_16x16x32_f16(a[0], b, acc[0][cf], 0, 0, 0);
            acc[1][cf] = __builtin_amdgcn_mfma_f32_16x16x32_f16(a[1], b, acc[1][cf], 0, 0, 0);
        }
    }

#pragma unroll
    for (int m = 0; m < 2; ++m)
#pragma unroll
        for (int r4 = 0; r4 < 4; ++r4) {
            int row = row0 + w * 32 + m * 16 + lg * 4 + r4;
            if (row < n) {
#pragma unroll
                for (int cf = 0; cf < 8; ++cf) {
                    int col = cf * 16 + lr;
                    g1[(size_t)row * DIM + col] = __float2half(acc[m][cf][r4]);
                }
            }
        }
}

// One WAVE per dst node, lane owns 2 features. ELL row + counts reads are
// wave-uniform -> scalarized. dinv recomputed as rsqrt(counts+1).
// 8 edges in flight, per-edge dinv[s] applied via fmaf.
__global__ void agg1_kernel(const __half* __restrict__ g1, const int* __restrict__ counts,
                            const int* __restrict__ col_ell, const int2* __restrict__ spill,
                            const float* __restrict__ b1, const float* __restrict__ W2,
                            float* __restrict__ g2, int n) {
    int lane = threadIdx.x & 63;
    int wid  = threadIdx.x >> 6;
    int d = blockIdx.x * 4 + wid;
    if (d >= n) return;
    int deg = __builtin_amdgcn_readfirstlane(counts[d]);
    float dv = rsqrtf((float)(deg + 1));
    const __half2* base = (const __half2*)g1 + lane;   // [n][64] half2
    float2 vf = __half22float2(base[(size_t)d * 64]);  // self loop
    float acc0 = dv * vf.x, acc1 = dv * vf.y;
    const int* row = col_ell + (size_t)d * ELLW;
    int m = deg < ELLW ? deg : ELLW;
    int j = 0;
    for (; j + 8 <= m; j += 8) {
        int s0 = row[j + 0], s1 = row[j + 1], s2 = row[j + 2], s3 = row[j + 3];
        int s4 = row[j + 4], s5 = row[j + 5], s6 = row[j + 6], s7 = row[j + 7];
        float w0 = rsqrtf((float)(counts[s0] + 1)), w1 = rsqrtf((float)(counts[s1] + 1));
        float w2 = rsqrtf((float)(counts[s2] + 1)), w3 = rsqrtf((float)(counts[s3] + 1));
        float w4 = rsqrtf((float)(counts[s4] + 1)), w5 = rsqrtf((float)(counts[s5] + 1));
        float w6 = rsqrtf((float)(counts[s6] + 1)), w7 = rsqrtf((float)(counts[s7] + 1));
        __half2 h0 = base[(size_t)s0 * 64], h1 = base[(size_t)s1 * 64];
        __half2 h2 = base[(size_t)s2 * 64], h3 = base[(size_t)s3 * 64];
        __half2 h4 = base[(size_t)s4 * 64], h5 = base[(size_t)s5 * 64];
        __half2 h6 = base[(size_t)s6 * 64], h7 = base[(size_t)s7 * 64];
        float2 u0 = __half22float2(h0), u1 = __half22float2(h1);
        float2 u2 = __half22float2(h2), u3 = __half22float2(h3);
        float2 u4 = __half22float2(h4), u5 = __half22float2(h5);
        float2 u6 = __half22float2(h6), u7 = __half22float2(h7);
        acc0 = fmaf(w0, u0.x, fmaf(w1, u1.x, fmaf(w2, u2.x, fmaf(w3, u3.x, acc0))));
        acc0 = fmaf(w4, u4.x, fmaf(w5, u5.x, fmaf(w6, u6.x, fmaf(w7, u7.x, acc0))));
        acc1 = fmaf(w0, u0.y, fmaf(w1, u1.y, fmaf(w2, u2.y, fmaf(w3, u3.y, acc1))));
        acc1 = fmaf(w4, u4.y, fmaf(w5, u5.y, fmaf(w6, u6.y, fmaf(w7, u7.y, acc1))));
    }
    for (; j < m; ++j) {
        int s = row[j];
        float ws = rsqrtf((float)(counts[s] + 1));
        float2 u = __half22float2(base[(size_t)s * 64]);
        acc0 = fmaf(ws, u.x, acc0);
        acc1 = fmaf(ws, u.y, acc1);
    }
    int sc = __builtin_amdgcn_readfirstlane(counts[n]);   // spill count (normally 0)
    if (sc > 0) {
        for (int i = 0; i < sc; ++i) {
            int2 sp = spill[i];
            if (sp.y == d) {
                float ws = rsqrtf((float)(counts[sp.x] + 1));
                float2 u = __half22float2(base[(size_t)sp.x * 64]);
                acc0 = fmaf(ws, u.x, acc0);
                acc1 = fmaf(ws, u.y, acc1);
            }
        }
    }
    int f0 = lane * 2, f1 = f0 + 1;
    float h0 = fmaxf(dv * acc0 + b1[f0], 0.f);
    float h1 = fmaxf(dv * acc1 + b1[f1], 0.f);
    float z0 = fmaf(h1, W2[f1 * 2 + 0], h0 * W2[f0 * 2 + 0]);
    float z1 = fmaf(h1, W2[f1 * 2 + 1], h0 * W2[f0 * 2 + 1]);
#pragma unroll
    for (int off = 32; off > 0; off >>= 1) {
        z0 += __shfl_down(z0, off);
        z1 += __shfl_down(z1, off);
    }
    if (lane == 0) {
        g2[d * 2 + 0] = dv * z0;
        g2[d * 2 + 1] = dv * z1;
    }
}

// Quarter-wave (16 lanes) per dst node: lane-per-edge ELL gather, 16-wide
// shuffle reduce, bias + log_softmax on sub-lane 0.
__global__ void agg2_kernel(const float* __restrict__ g2, const int* __restrict__ counts,
                            const int* __restrict__ col_ell, const int2* __restrict__ spill,
                            const float* __restrict__ b2, float* __restrict__ out, int n) {
    int t = threadIdx.x;
    int sub = t & 15;
    int d = blockIdx.x * 16 + (t >> 4);
    if (d >= n) return;
    int deg = counts[d];
    int m = deg < ELLW ? deg : ELLW;
    const int* row = col_ell + (size_t)d * ELLW;
    float a0 = 0.f, a1 = 0.f;
    const float2* g2v = (const float2*)g2;
    for (int j = sub; j < m; j += 16) {
        float2 v = g2v[row[j]];
        a0 += v.x; a1 += v.y;
    }
    int sc = counts[n];
    if (sc > 0 && sub == 0) {
        for (int i = 0; i < sc; ++i) {
            int2 sp = spill[i];
            if (sp.y == d) { float2 v = g2v[sp.x]; a0 += v.x; a1 += v.y; }
        }
    }
#pragma unroll
    for (int off = 8; off > 0; off >>= 1) {
        a0 += __shfl_down(a0, off, 16);
        a1 += __shfl_down(a1, off, 16);
    }
    if (sub == 0) {
        float2 self = g2v[d];
        float dv = rsqrtf((float)(deg + 1));
        float z0 = dv * (a0 + self.x) + b2[0];
        float z1 = dv * (a1 + self.y) + b2[1];
        float mm = fmaxf(z0, z1);
        float l = mm + logf(expf(z0 - mm) + expf(z1 - mm));
        out[d * 2 + 0] = z0 - l;
        out[d * 2 + 1] = z1 - l;
    }
}

extern "C" void kernel_launch(void* const* d_in, const int* in_sizes, int n_in,
                              void* d_out, int out_size, void* d_ws, size_t ws_size,
                              hipStream_t stream) {
    const float* x  = (const float*)d_in[0];
    const int*   ei = (const int*)d_in[1];
    const float* W1 = (const float*)d_in[2];
    const float* b1 = (const float*)d_in[3];
    const float* W2 = (const float*)d_in[4];
    const float* b2 = (const float*)d_in[5];
    float* out = (float*)d_out;

    int n = in_sizes[0] / DIM;   // 50000
    int e = in_sizes[1] / 2;     // 800000

    char* wsp = (char*)d_ws;
    size_t used = 0;
    auto alloc = [&](size_t bytes) {
        char* p = wsp + used;
        used += (bytes + 255) & ~(size_t)255;
        return p;
    };
    int*    counts  = (int*)alloc((size_t)(n + 64) * 4);   // [n] = spill counter
    int*    col_ell = (int*)alloc((size_t)n * ELLW * 4);   // 6.4 MB
    int2*   spill   = (int2*)alloc((size_t)e * 8);         // overflow edges
    __half* g1      = (__half*)alloc((size_t)n * DIM * 2);
    float*  g2      = (float*)alloc((size_t)n * 2 * 4);
    __half* W1T     = (__half*)alloc((size_t)DIM * DIM * 2);

    hipMemsetAsync(counts, 0, (size_t)(n + 64) * 4, stream);
    w1prep_kernel<<<4, 256, 0, stream>>>(W1, W1T);
    gemm1_kernel<<<(n + GR - 1) / GR, 256, 0, stream>>>(x, W1T, g1, n);
    long long nchunk = ((long long)e + 256 * EPC - 1) / (256 * EPC);
    count_ell_kernel<<<(unsigned)(nchunk * 8), 256, 0, stream>>>(ei, counts, col_ell, spill, n, e);
    agg1_kernel<<<(n + 3) / 4, 256, 0, stream>>>(g1, counts, col_ell, spill, b1, W2, g2, n);
    agg2_kernel<<<(n + 15) / 16, 256, 0, stream>>>(g2, counts, col_ell, spill, b2, out, n);
}

// Round 11
// 118.533 us; speedup vs baseline: 4.1142x; 1.0357x over previous
//
#include <hip/hip_runtime.h>
#include <hip/hip_fp16.h>

// ---------------------------------------------------------------------------
// GCN forward: 2-layer, fused normalization.
//   deg[d] = in_degree(d) + 1 (self loop);  dinv = rsqrt(deg)
//   g1 = fp16( dinv .* (x @ W1) )            [f16 MFMA; dinv in epilogue]
//   h  = relu(dinv[d] * (sum_{s->d} g1[s] + g1[d]) + b1)
//   g2 = dinv .* (h @ W2)                    (fused into agg1 epilogue)
//   z  = dinv[d] * (sum_{s->d} g2[s] + g2[d]) + b2
//   out = log_softmax(z)
// Graph: padded ELL (width 32) + spill list, built by XCD-class-partitioned
// scatter (class=(d>>4)&7, block class=blockIdx&7) -- every counts/col_ell
// line written by one XCD only (round-9: shared lines cost 48MB write-amp).
// count_ell runs BEFORE gemm1 so dinv folds into the g1 store (round-10:
// per-edge counts-gather+rsqrt in agg1 cost VALUBusy 53%, 50us).
// ---------------------------------------------------------------------------

#define DIM 128
#define ELLW 32
#define EPC 4          // edges per thread per class-block

typedef _Float16 f16x8 __attribute__((ext_vector_type(8)));
typedef float f32x4 __attribute__((ext_vector_type(4)));

// Per-block int64-vs-int32 detection: int64 edge_index has zero high words.
__device__ __forceinline__ int detect_is64(const int* __restrict__ ei, int e) {
    __shared__ int sflag;
    int t = threadIdx.x;
    int hv = (t < 32 && (2 * t + 1) < 2 * e) ? ei[2 * t + 1] : 0;
    unsigned long long nz = __ballot(hv != 0);
    if (t == 0) sflag = (nz == 0ULL) ? 1 : 0;
    __syncthreads();
    return sflag;
}

__device__ __forceinline__ int load_idx(const int* ei, long long pos, int is64) {
    if (is64) return (int)((const long long*)ei)[pos];
    return ei[pos];
}

// XCD-class-partitioned decode + count + ELL scatter.
// blockIdx&7 = class; block processes only edges with ((d>>4)&7)==class.
// counts[n] is the spill counter.
__global__ void count_ell_kernel(const int* __restrict__ ei, int* __restrict__ counts,
                                 int* __restrict__ col_ell, int2* __restrict__ spill,
                                 int n, int e) {
    int is64 = detect_is64(ei, e);
    int cls = blockIdx.x & 7;
    long long chunk = blockIdx.x >> 3;
    long long base = chunk * (256 * EPC) + threadIdx.x;
#pragma unroll
    for (int k = 0; k < EPC; ++k) {
        long long i = base + (long long)k * 256;
        if (i < e) {
            int d = load_idx(ei, (long long)e + i, is64);
            if (((d >> 4) & 7) == cls) {
                int s = load_idx(ei, i, is64);
                int tk = atomicAdd(&counts[d], 1);
                if (tk < ELLW) {
                    col_ell[(size_t)d * ELLW + tk] = s;
                } else {
                    int p = atomicAdd(&counts[n], 1);
                    spill[p] = make_int2(s, d);
                }
            }
        }
    }
}

// W1T[col][k] = f16(W1[k][col]); 4 blocks x 32 cols.
__global__ void w1prep_kernel(const float* __restrict__ W1, __half* __restrict__ W1T) {
    __shared__ __half wtile[32 * 136];
    int t = threadIdx.x;
    int c0 = blockIdx.x * 32;
    for (int it = 0; it < 16; ++it) {
        int k = it * 8 + (t >> 5);
        int c = t & 31;
        wtile[c * 136 + k] = __float2half(W1[(size_t)k * DIM + c0 + c]);
    }
    __syncthreads();
#pragma unroll
    for (int it = 0; it < 2; ++it) {
        int c = t >> 3;
        int kc = (t & 7) + it * 8;
        *(float4*)((char*)(W1T + (size_t)(c0 + c) * DIM) + kc * 16) =
            *(float4*)((char*)(wtile + c * 136) + kc * 16);
    }
}

// ---------------------------------------------------------------------------
// gemm1 (MFMA): g1 = f16(dinv .* (x @ W1)). 128x128 per block, 4 waves.
// xs/wt XOR-swizzled ((row&7)<<4). A/B frag outer=lane&15, k=(lane>>4)*8+j;
// C/D col=lane&15, row=(lane>>4)*4+reg. dinv=rsqrt(counts[row]+1) in epilogue.
// ---------------------------------------------------------------------------
#define GR 128
__global__ __launch_bounds__(256) void gemm1_kernel(
        const float* __restrict__ x, const __half* __restrict__ W1T,
        const int* __restrict__ counts, __half* __restrict__ g1, int n) {
    __shared__ short xs[GR * DIM];    // 32 KB
    __shared__ short wt[DIM * DIM];   // 32 KB
    int t = threadIdx.x;
    int row0 = blockIdx.x * GR;

#pragma unroll
    for (int i = 0; i < 8; ++i) {
        int f = t + i * 256;
        int col = f >> 4, kc = f & 15;
        unsigned int byte = (unsigned)(col * 256 + kc * 16);
        byte ^= (unsigned)((col & 7) << 4);
        *(float4*)((char*)wt + byte) = *(const float4*)((const char*)W1T + (size_t)f * 16);
    }
#pragma unroll
    for (int i = 0; i < 16; ++i) {
        int f = t + i * 256;
        int r = f >> 5, c4 = f & 31;
        float4 v = make_float4(0.f, 0.f, 0.f, 0.f);
        if (row0 + r < n)
            v = *(const float4*)(x + (size_t)(row0 + r) * DIM + c4 * 4);
        __half2 p01 = __floats2half2_rn(v.x, v.y);
        __half2 p23 = __floats2half2_rn(v.z, v.w);
        float2 pk;
        ((__half2*)&pk)[0] = p01;
        ((__half2*)&pk)[1] = p23;
        unsigned int byte = (unsigned)(r * 256 + c4 * 8);
        byte ^= (unsigned)((r & 7) << 4);
        *(float2*)((char*)xs + byte) = pk;
    }
    __syncthreads();

    int w  = t >> 6;
    int l  = t & 63;
    int lr = l & 15;
    int lg = l >> 4;

    f32x4 acc[2][8];
#pragma unroll
    for (int m = 0; m < 2; ++m)
#pragma unroll
        for (int cf = 0; cf < 8; ++cf) acc[m][cf] = (f32x4){0.f, 0.f, 0.f, 0.f};

#pragma unroll
    for (int kt = 0; kt < 4; ++kt) {
        int kByte = kt * 64 + lg * 16;
        f16x8 a[2];
#pragma unroll
        for (int m = 0; m < 2; ++m) {
            int row = w * 32 + m * 16 + lr;
            unsigned int byte = (unsigned)(row * 256 + kByte);
            byte ^= (unsigned)((row & 7) << 4);
            a[m] = *(const f16x8*)((const char*)xs + byte);
        }
#pragma unroll
        for (int cf = 0; cf < 8; ++cf) {
            int col = cf * 16 + lr;
            unsigned int byte = (unsigned)(col * 256 + kByte);
            byte ^= (unsigned)((col & 7) << 4);
            f16x8 b = *(const f16x8*)((const char*)wt + byte);
            acc[0][cf] = __builtin_amdgcn_mfma_f32_16x16x32_f16(a[0], b, acc[0][cf], 0, 0, 0);
            acc[1][cf] = __builtin_amdgcn_mfma_f32_16x16x32_f16(a[1], b, acc[1][cf], 0, 0, 0);
        }
    }

#pragma unroll
    for (int m = 0; m < 2; ++m)
#pragma unroll
        for (int r4 = 0; r4 < 4; ++r4) {
            int row = row0 + w * 32 + m * 16 + lg * 4 + r4;
            if (row < n) {
                float dv = rsqrtf((float)(counts[row] + 1));
#pragma unroll
                for (int cf = 0; cf < 8; ++cf) {
                    int col = cf * 16 + lr;
                    g1[(size_t)row * DIM + col] = __float2half(acc[m][cf][r4] * dv);
                }
            }
        }
}

// One WAVE per dst node, lane owns 2 features (half2; 256B/edge wave-wide).
// g1 rows pre-weighted by dinv[s] -> inner loop is pure gather+add.
// ELL row + counts reads wave-uniform -> scalarized. 8 edges in flight.
__global__ void agg1_kernel(const __half* __restrict__ g1, const int* __restrict__ counts,
                            const int* __restrict__ col_ell, const int2* __restrict__ spill,
                            const float* __restrict__ b1, const float* __restrict__ W2,
                            float* __restrict__ g2, int n) {
    int lane = threadIdx.x & 63;
    int wid  = threadIdx.x >> 6;
    int d = blockIdx.x * 4 + wid;
    if (d >= n) return;
    int deg = __builtin_amdgcn_readfirstlane(counts[d]);
    float dv = rsqrtf((float)(deg + 1));
    const __half2* base = (const __half2*)g1 + lane;   // [n][64] half2
    float2 vf = __half22float2(base[(size_t)d * 64]);  // self loop (pre-weighted)
    float acc0 = vf.x, acc1 = vf.y;
    const int* row = col_ell + (size_t)d * ELLW;
    int m = deg < ELLW ? deg : ELLW;
    int j = 0;
    for (; j + 8 <= m; j += 8) {
        int s0 = row[j + 0], s1 = row[j + 1], s2 = row[j + 2], s3 = row[j + 3];
        int s4 = row[j + 4], s5 = row[j + 5], s6 = row[j + 6], s7 = row[j + 7];
        __half2 h0 = base[(size_t)s0 * 64], h1 = base[(size_t)s1 * 64];
        __half2 h2 = base[(size_t)s2 * 64], h3 = base[(size_t)s3 * 64];
        __half2 h4 = base[(size_t)s4 * 64], h5 = base[(size_t)s5 * 64];
        __half2 h6 = base[(size_t)s6 * 64], h7 = base[(size_t)s7 * 64];
        float2 u0 = __half22float2(h0), u1 = __half22float2(h1);
        float2 u2 = __half22float2(h2), u3 = __half22float2(h3);
        float2 u4 = __half22float2(h4), u5 = __half22float2(h5);
        float2 u6 = __half22float2(h6), u7 = __half22float2(h7);
        acc0 += ((u0.x + u1.x) + (u2.x + u3.x)) + ((u4.x + u5.x) + (u6.x + u7.x));
        acc1 += ((u0.y + u1.y) + (u2.y + u3.y)) + ((u4.y + u5.y) + (u6.y + u7.y));
    }
    for (; j < m; ++j) {
        float2 u = __half22float2(base[(size_t)row[j] * 64]);
        acc0 += u.x; acc1 += u.y;
    }
    int sc = __builtin_amdgcn_readfirstlane(counts[n]);   // spill count (normally 0)
    if (sc > 0) {
        for (int i = 0; i < sc; ++i) {
            int2 sp = spill[i];
            if (sp.y == d) {
                float2 u = __half22float2(base[(size_t)sp.x * 64]);
                acc0 += u.x; acc1 += u.y;
            }
        }
    }
    int f0 = lane * 2, f1 = f0 + 1;
    float h0 = fmaxf(dv * acc0 + b1[f0], 0.f);
    float h1 = fmaxf(dv * acc1 + b1[f1], 0.f);
    float z0 = fmaf(h1, W2[f1 * 2 + 0], h0 * W2[f0 * 2 + 0]);
    float z1 = fmaf(h1, W2[f1 * 2 + 1], h0 * W2[f0 * 2 + 1]);
#pragma unroll
    for (int off = 32; off > 0; off >>= 1) {
        z0 += __shfl_down(z0, off);
        z1 += __shfl_down(z1, off);
    }
    if (lane == 0) {
        g2[d * 2 + 0] = dv * z0;
        g2[d * 2 + 1] = dv * z1;
    }
}

// Quarter-wave (16 lanes) per dst node: lane-per-edge ELL gather, 16-wide
// shuffle reduce, bias + log_softmax on sub-lane 0.
__global__ void agg2_kernel(const float* __restrict__ g2, const int* __restrict__ counts,
                            const int* __restrict__ col_ell, const int2* __restrict__ spill,
                            const float* __restrict__ b2, float* __restrict__ out, int n) {
    int t = threadIdx.x;
    int sub = t & 15;
    int d = blockIdx.x * 16 + (t >> 4);
    if (d >= n) return;
    int deg = counts[d];
    int m = deg < ELLW ? deg : ELLW;
    const int* row = col_ell + (size_t)d * ELLW;
    float a0 = 0.f, a1 = 0.f;
    const float2* g2v = (const float2*)g2;
    for (int j = sub; j < m; j += 16) {
        float2 v = g2v[row[j]];
        a0 += v.x; a1 += v.y;
    }
    int sc = counts[n];
    if (sc > 0 && sub == 0) {
        for (int i = 0; i < sc; ++i) {
            int2 sp = spill[i];
            if (sp.y == d) { float2 v = g2v[sp.x]; a0 += v.x; a1 += v.y; }
        }
    }
#pragma unroll
    for (int off = 8; off > 0; off >>= 1) {
        a0 += __shfl_down(a0, off, 16);
        a1 += __shfl_down(a1, off, 16);
    }
    if (sub == 0) {
        float2 self = g2v[d];
        float dv = rsqrtf((float)(deg + 1));
        float z0 = dv * (a0 + self.x) + b2[0];
        float z1 = dv * (a1 + self.y) + b2[1];
        float mm = fmaxf(z0, z1);
        float l = mm + logf(expf(z0 - mm) + expf(z1 - mm));
        out[d * 2 + 0] = z0 - l;
        out[d * 2 + 1] = z1 - l;
    }
}

extern "C" void kernel_launch(void* const* d_in, const int* in_sizes, int n_in,
                              void* d_out, int out_size, void* d_ws, size_t ws_size,
                              hipStream_t stream) {
    const float* x  = (const float*)d_in[0];
    const int*   ei = (const int*)d_in[1];
    const float* W1 = (const float*)d_in[2];
    const float* b1 = (const float*)d_in[3];
    const float* W2 = (const float*)d_in[4];
    const float* b2 = (const float*)d_in[5];
    float* out = (float*)d_out;

    int n = in_sizes[0] / DIM;   // 50000
    int e = in_sizes[1] / 2;     // 800000

    char* wsp = (char*)d_ws;
    size_t used = 0;
    auto alloc = [&](size_t bytes) {
        char* p = wsp + used;
        used += (bytes + 255) & ~(size_t)255;
        return p;
    };
    int*    counts  = (int*)alloc((size_t)(n + 64) * 4);   // [n] = spill counter
    int*    col_ell = (int*)alloc((size_t)n * ELLW * 4);   // 6.4 MB
    int2*   spill   = (int2*)alloc((size_t)e * 8);         // overflow edges
    __half* g1      = (__half*)alloc((size_t)n * DIM * 2);
    float*  g2      = (float*)alloc((size_t)n * 2 * 4);
    __half* W1T     = (__half*)alloc((size_t)DIM * DIM * 2);

    hipMemsetAsync(counts, 0, (size_t)(n + 64) * 4, stream);
    w1prep_kernel<<<4, 256, 0, stream>>>(W1, W1T);
    long long nchunk = ((long long)e + 256 * EPC - 1) / (256 * EPC);
    count_ell_kernel<<<(unsigned)(nchunk * 8), 256, 0, stream>>>(ei, counts, col_ell, spill, n, e);
    gemm1_kernel<<<(n + GR - 1) / GR, 256, 0, stream>>>(x, W1T, counts, g1, n);
    agg1_kernel<<<(n + 3) / 4, 256, 0, stream>>>(g1, counts, col_ell, spill, b1, W2, g2, n);
    agg2_kernel<<<(n + 15) / 16, 256, 0, stream>>>(g2, counts, col_ell, spill, b2, out, n);
}

// Round 12
// 110.005 us; speedup vs baseline: 4.4332x; 1.0775x over previous
//
#include <hip/hip_runtime.h>
#include <hip/hip_fp16.h>

// ---------------------------------------------------------------------------
// GCN forward: 2-layer, fused normalization.
//   deg[d] = in_degree(d) + 1 (self loop);  dinv = rsqrt(deg)
//   g1 = fp16( dinv .* (x @ W1) )            [f16 MFMA; dinv in epilogue]
//   h  = relu(dinv[d] * (sum_{s->d} g1[s] + g1[d]) + b1)
//   g2 = dinv .* (h @ W2)                    (fused into agg1 epilogue)
//   z  = dinv[d] * (sum_{s->d} g2[s] + g2[d]) + b2
//   out = log_softmax(z)
// Graph: padded ELL (width 32) + spill list, XCD-class-partitioned build
// (round-9: shared lines cost 48MB write-amp). count_ell before gemm1 so
// dinv folds into g1 store (round-10 lesson). agg1 round-12 change: read all
// 32 ELL indices as SCALARS up front, clamp pads to zero-row g1[n] (L1-hit),
// issue all 32 gathers back-to-back -> 4x the in-flight loads per wave
// (round-11: 8-deep batches were latency-bound at 30% VALU, 4.5TB/s).
// ---------------------------------------------------------------------------

#define DIM 128
#define ELLW 32
#define EPC 4          // edges per thread per class-block

typedef _Float16 f16x8 __attribute__((ext_vector_type(8)));
typedef float f32x4 __attribute__((ext_vector_type(4)));

// Per-block int64-vs-int32 detection: int64 edge_index has zero high words.
__device__ __forceinline__ int detect_is64(const int* __restrict__ ei, int e) {
    __shared__ int sflag;
    int t = threadIdx.x;
    int hv = (t < 32 && (2 * t + 1) < 2 * e) ? ei[2 * t + 1] : 0;
    unsigned long long nz = __ballot(hv != 0);
    if (t == 0) sflag = (nz == 0ULL) ? 1 : 0;
    __syncthreads();
    return sflag;
}

__device__ __forceinline__ int load_idx(const int* ei, long long pos, int is64) {
    if (is64) return (int)((const long long*)ei)[pos];
    return ei[pos];
}

// XCD-class-partitioned decode + count + ELL scatter.
// blockIdx&7 = class; block processes only edges with ((d>>4)&7)==class.
// counts[n] is the spill counter.
__global__ void count_ell_kernel(const int* __restrict__ ei, int* __restrict__ counts,
                                 int* __restrict__ col_ell, int2* __restrict__ spill,
                                 int n, int e) {
    int is64 = detect_is64(ei, e);
    int cls = blockIdx.x & 7;
    long long chunk = blockIdx.x >> 3;
    long long base = chunk * (256 * EPC) + threadIdx.x;
#pragma unroll
    for (int k = 0; k < EPC; ++k) {
        long long i = base + (long long)k * 256;
        if (i < e) {
            int d = load_idx(ei, (long long)e + i, is64);
            if (((d >> 4) & 7) == cls) {
                int s = load_idx(ei, i, is64);
                int tk = atomicAdd(&counts[d], 1);
                if (tk < ELLW) {
                    col_ell[(size_t)d * ELLW + tk] = s;
                } else {
                    int p = atomicAdd(&counts[n], 1);
                    spill[p] = make_int2(s, d);
                }
            }
        }
    }
}

// W1T[col][k] = f16(W1[k][col]); 4 blocks x 32 cols.
__global__ void w1prep_kernel(const float* __restrict__ W1, __half* __restrict__ W1T) {
    __shared__ __half wtile[32 * 136];
    int t = threadIdx.x;
    int c0 = blockIdx.x * 32;
    for (int it = 0; it < 16; ++it) {
        int k = it * 8 + (t >> 5);
        int c = t & 31;
        wtile[c * 136 + k] = __float2half(W1[(size_t)k * DIM + c0 + c]);
    }
    __syncthreads();
#pragma unroll
    for (int it = 0; it < 2; ++it) {
        int c = t >> 3;
        int kc = (t & 7) + it * 8;
        *(float4*)((char*)(W1T + (size_t)(c0 + c) * DIM) + kc * 16) =
            *(float4*)((char*)(wtile + c * 136) + kc * 16);
    }
}

// ---------------------------------------------------------------------------
// gemm1 (MFMA): g1 = f16(dinv .* (x @ W1)). 128x128 per block, 4 waves.
// xs/wt XOR-swizzled ((row&7)<<4). A/B frag outer=lane&15, k=(lane>>4)*8+j;
// C/D col=lane&15, row=(lane>>4)*4+reg. dinv=rsqrt(counts[row]+1) in epilogue.
// ---------------------------------------------------------------------------
#define GR 128
__global__ __launch_bounds__(256) void gemm1_kernel(
        const float* __restrict__ x, const __half* __restrict__ W1T,
        const int* __restrict__ counts, __half* __restrict__ g1, int n) {
    __shared__ short xs[GR * DIM];    // 32 KB
    __shared__ short wt[DIM * DIM];   // 32 KB
    int t = threadIdx.x;
    int row0 = blockIdx.x * GR;

#pragma unroll
    for (int i = 0; i < 8; ++i) {
        int f = t + i * 256;
        int col = f >> 4, kc = f & 15;
        unsigned int byte = (unsigned)(col * 256 + kc * 16);
        byte ^= (unsigned)((col & 7) << 4);
        *(float4*)((char*)wt + byte) = *(const float4*)((const char*)W1T + (size_t)f * 16);
    }
#pragma unroll
    for (int i = 0; i < 16; ++i) {
        int f = t + i * 256;
        int r = f >> 5, c4 = f & 31;
        float4 v = make_float4(0.f, 0.f, 0.f, 0.f);
        if (row0 + r < n)
            v = *(const float4*)(x + (size_t)(row0 + r) * DIM + c4 * 4);
        __half2 p01 = __floats2half2_rn(v.x, v.y);
        __half2 p23 = __floats2half2_rn(v.z, v.w);
        float2 pk;
        ((__half2*)&pk)[0] = p01;
        ((__half2*)&pk)[1] = p23;
        unsigned int byte = (unsigned)(r * 256 + c4 * 8);
        byte ^= (unsigned)((r & 7) << 4);
        *(float2*)((char*)xs + byte) = pk;
    }
    __syncthreads();

    int w  = t >> 6;
    int l  = t & 63;
    int lr = l & 15;
    int lg = l >> 4;

    f32x4 acc[2][8];
#pragma unroll
    for (int m = 0; m < 2; ++m)
#pragma unroll
        for (int cf = 0; cf < 8; ++cf) acc[m][cf] = (f32x4){0.f, 0.f, 0.f, 0.f};

#pragma unroll
    for (int kt = 0; kt < 4; ++kt) {
        int kByte = kt * 64 + lg * 16;
        f16x8 a[2];
#pragma unroll
        for (int m = 0; m < 2; ++m) {
            int row = w * 32 + m * 16 + lr;
            unsigned int byte = (unsigned)(row * 256 + kByte);
            byte ^= (unsigned)((row & 7) << 4);
            a[m] = *(const f16x8*)((const char*)xs + byte);
        }
#pragma unroll
        for (int cf = 0; cf < 8; ++cf) {
            int col = cf * 16 + lr;
            unsigned int byte = (unsigned)(col * 256 + kByte);
            byte ^= (unsigned)((col & 7) << 4);
            f16x8 b = *(const f16x8*)((const char*)wt + byte);
            acc[0][cf] = __builtin_amdgcn_mfma_f32_16x16x32_f16(a[0], b, acc[0][cf], 0, 0, 0);
            acc[1][cf] = __builtin_amdgcn_mfma_f32_16x16x32_f16(a[1], b, acc[1][cf], 0, 0, 0);
        }
    }

#pragma unroll
    for (int m = 0; m < 2; ++m)
#pragma unroll
        for (int r4 = 0; r4 < 4; ++r4) {
            int row = row0 + w * 32 + m * 16 + lg * 4 + r4;
            if (row < n) {
                float dv = rsqrtf((float)(counts[row] + 1));
#pragma unroll
                for (int cf = 0; cf < 8; ++cf) {
                    int col = cf * 16 + lr;
                    g1[(size_t)row * DIM + col] = __float2half(acc[m][cf][r4] * dv);
                }
            }
        }
}

// One WAVE per dst node, lane owns 2 features (half2; 256B/edge wave-wide).
// All 32 ELL indices read as scalars up front; pad slots (k>=deg) clamped to
// the zero row g1[n] (same 256B line -> L1 hit, contributes 0). All 32
// gathers issue back-to-back: max memory-level parallelism per wave.
__global__ void agg1_kernel(const __half* __restrict__ g1, const int* __restrict__ counts,
                            const int* __restrict__ col_ell, const int2* __restrict__ spill,
                            const float* __restrict__ b1, const float* __restrict__ W2,
                            float* __restrict__ g2, int n) {
    int lane = threadIdx.x & 63;
    int wid  = threadIdx.x >> 6;
    int d = blockIdx.x * 4 + wid;
    if (d >= n) return;
    int deg = __builtin_amdgcn_readfirstlane(counts[d]);
    float dv = rsqrtf((float)(deg + 1));
    const __half2* base = (const __half2*)g1 + lane;   // [n+1][64] half2
    int m = deg < ELLW ? deg : ELLW;
    const int* row = col_ell + (size_t)d * ELLW;

    int idx[ELLW];
#pragma unroll
    for (int k = 0; k < ELLW; ++k) {
        int s = __builtin_amdgcn_readfirstlane(row[k]);  // scalar load
        idx[k] = (k < m) ? s : n;                        // scalar select (pad->zero row)
    }
    __half2 h[ELLW];
#pragma unroll
    for (int k = 0; k < ELLW; ++k)
        h[k] = base[(size_t)idx[k] * 64];                // 32 loads in flight
    float2 vf = __half22float2(base[(size_t)d * 64]);    // self loop (pre-weighted)
    float a0 = vf.x, a1 = vf.y, c0 = 0.f, c1 = 0.f;      // 2 chains
#pragma unroll
    for (int k = 0; k < ELLW; k += 2) {
        float2 u = __half22float2(h[k]);
        float2 v = __half22float2(h[k + 1]);
        a0 += u.x; a1 += u.y;
        c0 += v.x; c1 += v.y;
    }
    float acc0 = a0 + c0, acc1 = a1 + c1;

    int sc = __builtin_amdgcn_readfirstlane(counts[n]);  // spill count (normally 0)
    if (sc > 0) {
        for (int i = 0; i < sc; ++i) {
            int2 sp = spill[i];
            if (sp.y == d) {
                float2 u = __half22float2(base[(size_t)sp.x * 64]);
                acc0 += u.x; acc1 += u.y;
            }
        }
    }
    int f0 = lane * 2, f1 = f0 + 1;
    float h0 = fmaxf(dv * acc0 + b1[f0], 0.f);
    float h1 = fmaxf(dv * acc1 + b1[f1], 0.f);
    float z0 = fmaf(h1, W2[f1 * 2 + 0], h0 * W2[f0 * 2 + 0]);
    float z1 = fmaf(h1, W2[f1 * 2 + 1], h0 * W2[f0 * 2 + 1]);
#pragma unroll
    for (int off = 32; off > 0; off >>= 1) {
        z0 += __shfl_down(z0, off);
        z1 += __shfl_down(z1, off);
    }
    if (lane == 0) {
        g2[d * 2 + 0] = dv * z0;
        g2[d * 2 + 1] = dv * z1;
    }
}

// Quarter-wave (16 lanes) per dst node: lane-per-edge ELL gather, 16-wide
// shuffle reduce, bias + log_softmax on sub-lane 0.
__global__ void agg2_kernel(const float* __restrict__ g2, const int* __restrict__ counts,
                            const int* __restrict__ col_ell, const int2* __restrict__ spill,
                            const float* __restrict__ b2, float* __restrict__ out, int n) {
    int t = threadIdx.x;
    int sub = t & 15;
    int d = blockIdx.x * 16 + (t >> 4);
    if (d >= n) return;
    int deg = counts[d];
    int m = deg < ELLW ? deg : ELLW;
    const int* row = col_ell + (size_t)d * ELLW;
    float a0 = 0.f, a1 = 0.f;
    const float2* g2v = (const float2*)g2;
    for (int j = sub; j < m; j += 16) {
        float2 v = g2v[row[j]];
        a0 += v.x; a1 += v.y;
    }
    int sc = counts[n];
    if (sc > 0 && sub == 0) {
        for (int i = 0; i < sc; ++i) {
            int2 sp = spill[i];
            if (sp.y == d) { float2 v = g2v[sp.x]; a0 += v.x; a1 += v.y; }
        }
    }
#pragma unroll
    for (int off = 8; off > 0; off >>= 1) {
        a0 += __shfl_down(a0, off, 16);
        a1 += __shfl_down(a1, off, 16);
    }
    if (sub == 0) {
        float2 self = g2v[d];
        float dv = rsqrtf((float)(deg + 1));
        float z0 = dv * (a0 + self.x) + b2[0];
        float z1 = dv * (a1 + self.y) + b2[1];
        float mm = fmaxf(z0, z1);
        float l = mm + logf(expf(z0 - mm) + expf(z1 - mm));
        out[d * 2 + 0] = z0 - l;
        out[d * 2 + 1] = z1 - l;
    }
}

extern "C" void kernel_launch(void* const* d_in, const int* in_sizes, int n_in,
                              void* d_out, int out_size, void* d_ws, size_t ws_size,
                              hipStream_t stream) {
    const float* x  = (const float*)d_in[0];
    const int*   ei = (const int*)d_in[1];
    const float* W1 = (const float*)d_in[2];
    const float* b1 = (const float*)d_in[3];
    const float* W2 = (const float*)d_in[4];
    const float* b2 = (const float*)d_in[5];
    float* out = (float*)d_out;

    int n = in_sizes[0] / DIM;   // 50000
    int e = in_sizes[1] / 2;     // 800000

    char* wsp = (char*)d_ws;
    size_t used = 0;
    auto alloc = [&](size_t bytes) {
        char* p = wsp + used;
        used += (bytes + 255) & ~(size_t)255;
        return p;
    };
    int*    counts  = (int*)alloc((size_t)(n + 64) * 4);       // [n] = spill counter
    int*    col_ell = (int*)alloc((size_t)n * ELLW * 4);       // 6.4 MB
    int2*   spill   = (int2*)alloc((size_t)e * 8);             // overflow edges
    __half* g1      = (__half*)alloc((size_t)(n + 1) * DIM * 2); // +1 zero row
    float*  g2      = (float*)alloc((size_t)n * 2 * 4);
    __half* W1T     = (__half*)alloc((size_t)DIM * DIM * 2);

    hipMemsetAsync(counts, 0, (size_t)(n + 64) * 4, stream);
    hipMemsetAsync(g1 + (size_t)n * DIM, 0, DIM * 2, stream);  // zero row
    w1prep_kernel<<<4, 256, 0, stream>>>(W1, W1T);
    long long nchunk = ((long long)e + 256 * EPC - 1) / (256 * EPC);
    count_ell_kernel<<<(unsigned)(nchunk * 8), 256, 0, stream>>>(ei, counts, col_ell, spill, n, e);
    gemm1_kernel<<<(n + GR - 1) / GR, 256, 0, stream>>>(x, W1T, counts, g1, n);
    agg1_kernel<<<(n + 3) / 4, 256, 0, stream>>>(g1, counts, col_ell, spill, b1, W2, g2, n);
    agg2_kernel<<<(n + 15) / 16, 256, 0, stream>>>(g2, counts, col_ell, spill, b2, out, n);
}

// Round 13
// 105.364 us; speedup vs baseline: 4.6285x; 1.0440x over previous
//
#include <hip/hip_runtime.h>
#include <hip/hip_fp16.h>

// ---------------------------------------------------------------------------
// GCN forward: 2-layer, fused normalization.
//   deg[d] = in_degree(d) + 1 (self loop);  dinv = rsqrt(deg)
//   g1 = fp16( dinv .* (x @ W1) )            [f16 MFMA; dinv in epilogue]
//   h  = relu(dinv[d] * (sum_{s->d} g1[s] + g1[d]) + b1)
//   g2 = dinv .* (h @ W2)                    (fused into agg1 epilogue)
//   z  = dinv[d] * (sum_{s->d} g2[s] + g2[d]) + b2
//   out = log_softmax(z)
// Graph: padded ELL (width 32) + spill, XCD-class-partitioned build
// (class=(d>>4)&7, writer blockIdx&7==class; round-9: shared lines = 48MB
// write-amp). Round-13: agg1/agg2 dispatch is class-ALIGNED too, so each
// node's col_ell/counts lines are read on the XCD whose L2 owns them, and
// g2 writes stay XCD-local. prep_kernel fuses W1T build + counts/zero-row
// clear (launches 8->6). agg1 reads all 32 ELL indices as scalars, pads to
// zero-row g1[n], 32 gathers in flight (round-12: +8.5us).
// ---------------------------------------------------------------------------

#define DIM 128
#define ELLW 32
#define EPC 4          // edges per thread per class-block in count_ell

typedef _Float16 f16x8 __attribute__((ext_vector_type(8)));
typedef float f32x4 __attribute__((ext_vector_type(4)));

// Per-block int64-vs-int32 detection: int64 edge_index has zero high words.
__device__ __forceinline__ int detect_is64(const int* __restrict__ ei, int e) {
    __shared__ int sflag;
    int t = threadIdx.x;
    int hv = (t < 32 && (2 * t + 1) < 2 * e) ? ei[2 * t + 1] : 0;
    unsigned long long nz = __ballot(hv != 0);
    if (t == 0) sflag = (nz == 0ULL) ? 1 : 0;
    __syncthreads();
    return sflag;
}

__device__ __forceinline__ int load_idx(const int* ei, long long pos, int is64) {
    if (is64) return (int)((const long long*)ei)[pos];
    return ei[pos];
}

// Per-class node count and j->d mapping (class = bits [4:6] of d).
__device__ __forceinline__ int class_count(int n, int cls) {
    int B = n >> 7, r = n & 127;
    int extra = r - cls * 16;
    extra = extra < 0 ? 0 : (extra > 16 ? 16 : extra);
    return B * 16 + extra;
}
__device__ __forceinline__ int class_node(int cls, int j) {
    return ((j >> 4) << 7) + cls * 16 + (j & 15);
}

// prep: blocks 0..3 build W1T[col][k]=f16(W1[k][col]); blocks 4..35 zero
// counts[n+64]; block 4 also zeros the g1 pad row.
__global__ void prep_kernel(const float* __restrict__ W1, __half* __restrict__ W1T,
                            int* __restrict__ counts, __half* __restrict__ g1zero, int n) {
    __shared__ __half wtile[32 * 136];
    int b = blockIdx.x;
    int t = threadIdx.x;
    if (b < 4) {
        int c0 = b * 32;
        for (int it = 0; it < 16; ++it) {
            int k = it * 8 + (t >> 5);
            int c = t & 31;
            wtile[c * 136 + k] = __float2half(W1[(size_t)k * DIM + c0 + c]);
        }
        __syncthreads();
#pragma unroll
        for (int it = 0; it < 2; ++it) {
            int c = t >> 3;
            int kc = (t & 7) + it * 8;
            *(float4*)((char*)(W1T + (size_t)(c0 + c) * DIM) + kc * 16) =
                *(float4*)((char*)(wtile + c * 136) + kc * 16);
        }
    } else {
        int zb = b - 4;                    // 0..31
        int total = n + 64;
        int per = (total + 31) / 32;
        int beg = zb * per;
        int end = beg + per; if (end > total) end = total;
        for (int i = beg + t; i < end; i += 256) counts[i] = 0;
        if (zb == 0 && t < 64) ((int*)g1zero)[t] = 0;
    }
}

// XCD-class-partitioned decode + count + ELL scatter. blockIdx&7 = class;
// block processes only edges with ((d>>4)&7)==class. counts[n] = spill ctr.
__global__ void count_ell_kernel(const int* __restrict__ ei, int* __restrict__ counts,
                                 int* __restrict__ col_ell, int2* __restrict__ spill,
                                 int n, int e) {
    int is64 = detect_is64(ei, e);
    int cls = blockIdx.x & 7;
    long long chunk = blockIdx.x >> 3;
    long long base = chunk * (256 * EPC) + threadIdx.x;
#pragma unroll
    for (int k = 0; k < EPC; ++k) {
        long long i = base + (long long)k * 256;
        if (i < e) {
            int d = load_idx(ei, (long long)e + i, is64);
            if (((d >> 4) & 7) == cls) {
                int s = load_idx(ei, i, is64);
                int tk = atomicAdd(&counts[d], 1);
                if (tk < ELLW) {
                    col_ell[(size_t)d * ELLW + tk] = s;
                } else {
                    int p = atomicAdd(&counts[n], 1);
                    spill[p] = make_int2(s, d);
                }
            }
        }
    }
}

// ---------------------------------------------------------------------------
// gemm1 (MFMA): g1 = f16(dinv .* (x @ W1)). 128x128 per block, 4 waves.
// xs/wt XOR-swizzled ((row&7)<<4). A/B frag outer=lane&15, k=(lane>>4)*8+j;
// C/D col=lane&15, row=(lane>>4)*4+reg. dinv=rsqrt(counts[row]+1) in epilogue.
// ---------------------------------------------------------------------------
#define GR 128
__global__ __launch_bounds__(256) void gemm1_kernel(
        const float* __restrict__ x, const __half* __restrict__ W1T,
        const int* __restrict__ counts, __half* __restrict__ g1, int n) {
    __shared__ short xs[GR * DIM];    // 32 KB
    __shared__ short wt[DIM * DIM];   // 32 KB
    int t = threadIdx.x;
    int row0 = blockIdx.x * GR;

#pragma unroll
    for (int i = 0; i < 8; ++i) {
        int f = t + i * 256;
        int col = f >> 4, kc = f & 15;
        unsigned int byte = (unsigned)(col * 256 + kc * 16);
        byte ^= (unsigned)((col & 7) << 4);
        *(float4*)((char*)wt + byte) = *(const float4*)((const char*)W1T + (size_t)f * 16);
    }
#pragma unroll
    for (int i = 0; i < 16; ++i) {
        int f = t + i * 256;
        int r = f >> 5, c4 = f & 31;
        float4 v = make_float4(0.f, 0.f, 0.f, 0.f);
        if (row0 + r < n)
            v = *(const float4*)(x + (size_t)(row0 + r) * DIM + c4 * 4);
        __half2 p01 = __floats2half2_rn(v.x, v.y);
        __half2 p23 = __floats2half2_rn(v.z, v.w);
        float2 pk;
        ((__half2*)&pk)[0] = p01;
        ((__half2*)&pk)[1] = p23;
        unsigned int byte = (unsigned)(r * 256 + c4 * 8);
        byte ^= (unsigned)((r & 7) << 4);
        *(float2*)((char*)xs + byte) = pk;
    }
    __syncthreads();

    int w  = t >> 6;
    int l  = t & 63;
    int lr = l & 15;
    int lg = l >> 4;

    f32x4 acc[2][8];
#pragma unroll
    for (int m = 0; m < 2; ++m)
#pragma unroll
        for (int cf = 0; cf < 8; ++cf) acc[m][cf] = (f32x4){0.f, 0.f, 0.f, 0.f};

#pragma unroll
    for (int kt = 0; kt < 4; ++kt) {
        int kByte = kt * 64 + lg * 16;
        f16x8 a[2];
#pragma unroll
        for (int m = 0; m < 2; ++m) {
            int row = w * 32 + m * 16 + lr;
            unsigned int byte = (unsigned)(row * 256 + kByte);
            byte ^= (unsigned)((row & 7) << 4);
            a[m] = *(const f16x8*)((const char*)xs + byte);
        }
#pragma unroll
        for (int cf = 0; cf < 8; ++cf) {
            int col = cf * 16 + lr;
            unsigned int byte = (unsigned)(col * 256 + kByte);
            byte ^= (unsigned)((col & 7) << 4);
            f16x8 b = *(const f16x8*)((const char*)wt + byte);
            acc[0][cf] = __builtin_amdgcn_mfma_f32_16x16x32_f16(a[0], b, acc[0][cf], 0, 0, 0);
            acc[1][cf] = __builtin_amdgcn_mfma_f32_16x16x32_f16(a[1], b, acc[1][cf], 0, 0, 0);
        }
    }

#pragma unroll
    for (int m = 0; m < 2; ++m)
#pragma unroll
        for (int r4 = 0; r4 < 4; ++r4) {
            int row = row0 + w * 32 + m * 16 + lg * 4 + r4;
            if (row < n) {
                float dv = rsqrtf((float)(counts[row] + 1));
#pragma unroll
                for (int cf = 0; cf < 8; ++cf) {
                    int col = cf * 16 + lr;
                    g1[(size_t)row * DIM + col] = __float2half(acc[m][cf][r4] * dv);
                }
            }
        }
}

// One WAVE per dst node, class-aligned: blockIdx&7 == (d>>4)&7 so col_ell/
// counts lines are local to the owning XCD's L2 and g2 writes stay local.
// All 32 ELL indices read as scalars up front; pads clamp to zero row g1[n];
// 32 gathers issue back-to-back (max MLP).
__global__ void agg1_kernel(const __half* __restrict__ g1, const int* __restrict__ counts,
                            const int* __restrict__ col_ell, const int2* __restrict__ spill,
                            const float* __restrict__ b1, const float* __restrict__ W2,
                            float* __restrict__ g2, int n) {
    int lane = threadIdx.x & 63;
    int wid  = threadIdx.x >> 6;
    int cls  = blockIdx.x & 7;
    int q    = blockIdx.x >> 3;
    int j    = q * 4 + wid;
    if (j >= class_count(n, cls)) return;
    int d = class_node(cls, j);
    int deg = __builtin_amdgcn_readfirstlane(counts[d]);
    float dv = rsqrtf((float)(deg + 1));
    const __half2* base = (const __half2*)g1 + lane;   // [n+1][64] half2
    int m = deg < ELLW ? deg : ELLW;
    const int* row = col_ell + (size_t)d * ELLW;

    int idx[ELLW];
#pragma unroll
    for (int k = 0; k < ELLW; ++k) {
        int s = __builtin_amdgcn_readfirstlane(row[k]);  // scalar load
        idx[k] = (k < m) ? s : n;                        // pad -> zero row
    }
    __half2 h[ELLW];
#pragma unroll
    for (int k = 0; k < ELLW; ++k)
        h[k] = base[(size_t)idx[k] * 64];                // 32 loads in flight
    float2 vf = __half22float2(base[(size_t)d * 64]);    // self loop (pre-weighted)
    float a0 = vf.x, a1 = vf.y, c0 = 0.f, c1 = 0.f;      // 2 chains
#pragma unroll
    for (int k = 0; k < ELLW; k += 2) {
        float2 u = __half22float2(h[k]);
        float2 v = __half22float2(h[k + 1]);
        a0 += u.x; a1 += u.y;
        c0 += v.x; c1 += v.y;
    }
    float acc0 = a0 + c0, acc1 = a1 + c1;

    int sc = __builtin_amdgcn_readfirstlane(counts[n]);  // spill count (normally 0)
    if (sc > 0) {
        for (int i = 0; i < sc; ++i) {
            int2 sp = spill[i];
            if (sp.y == d) {
                float2 u = __half22float2(base[(size_t)sp.x * 64]);
                acc0 += u.x; acc1 += u.y;
            }
        }
    }
    int f0 = lane * 2, f1 = f0 + 1;
    float h0 = fmaxf(dv * acc0 + b1[f0], 0.f);
    float h1 = fmaxf(dv * acc1 + b1[f1], 0.f);
    float z0 = fmaf(h1, W2[f1 * 2 + 0], h0 * W2[f0 * 2 + 0]);
    float z1 = fmaf(h1, W2[f1 * 2 + 1], h0 * W2[f0 * 2 + 1]);
#pragma unroll
    for (int off = 32; off > 0; off >>= 1) {
        z0 += __shfl_down(z0, off);
        z1 += __shfl_down(z1, off);
    }
    if (lane == 0) {
        g2[d * 2 + 0] = dv * z0;
        g2[d * 2 + 1] = dv * z1;
    }
}

// Quarter-wave (16 lanes) per dst node, class-aligned like agg1.
__global__ void agg2_kernel(const float* __restrict__ g2, const int* __restrict__ counts,
                            const int* __restrict__ col_ell, const int2* __restrict__ spill,
                            const float* __restrict__ b2, float* __restrict__ out, int n) {
    int t = threadIdx.x;
    int sub = t & 15;
    int cls = blockIdx.x & 7;
    int q   = blockIdx.x >> 3;
    int j   = q * 16 + (t >> 4);
    if (j >= class_count(n, cls)) return;
    int d = class_node(cls, j);
    int deg = counts[d];
    int m = deg < ELLW ? deg : ELLW;
    const int* row = col_ell + (size_t)d * ELLW;
    float a0 = 0.f, a1 = 0.f;
    const float2* g2v = (const float2*)g2;
    for (int jj = sub; jj < m; jj += 16) {
        float2 v = g2v[row[jj]];
        a0 += v.x; a1 += v.y;
    }
    int sc = counts[n];
    if (sc > 0 && sub == 0) {
        for (int i = 0; i < sc; ++i) {
            int2 sp = spill[i];
            if (sp.y == d) { float2 v = g2v[sp.x]; a0 += v.x; a1 += v.y; }
        }
    }
#pragma unroll
    for (int off = 8; off > 0; off >>= 1) {
        a0 += __shfl_down(a0, off, 16);
        a1 += __shfl_down(a1, off, 16);
    }
    if (sub == 0) {
        float2 self = g2v[d];
        float dv = rsqrtf((float)(deg + 1));
        float z0 = dv * (a0 + self.x) + b2[0];
        float z1 = dv * (a1 + self.y) + b2[1];
        float mm = fmaxf(z0, z1);
        float l = mm + logf(expf(z0 - mm) + expf(z1 - mm));
        out[d * 2 + 0] = z0 - l;
        out[d * 2 + 1] = z1 - l;
    }
}

extern "C" void kernel_launch(void* const* d_in, const int* in_sizes, int n_in,
                              void* d_out, int out_size, void* d_ws, size_t ws_size,
                              hipStream_t stream) {
    const float* x  = (const float*)d_in[0];
    const int*   ei = (const int*)d_in[1];
    const float* W1 = (const float*)d_in[2];
    const float* b1 = (const float*)d_in[3];
    const float* W2 = (const float*)d_in[4];
    const float* b2 = (const float*)d_in[5];
    float* out = (float*)d_out;

    int n = in_sizes[0] / DIM;   // 50000
    int e = in_sizes[1] / 2;     // 800000

    char* wsp = (char*)d_ws;
    size_t used = 0;
    auto alloc = [&](size_t bytes) {
        char* p = wsp + used;
        used += (bytes + 255) & ~(size_t)255;
        return p;
    };
    int*    counts  = (int*)alloc((size_t)(n + 64) * 4);         // [n] = spill ctr
    int*    col_ell = (int*)alloc((size_t)n * ELLW * 4);         // 6.4 MB
    int2*   spill   = (int2*)alloc((size_t)e * 8);               // overflow edges
    __half* g1      = (__half*)alloc((size_t)(n + 1) * DIM * 2); // +1 zero row
    float*  g2      = (float*)alloc((size_t)n * 2 * 4);
    __half* W1T     = (__half*)alloc((size_t)DIM * DIM * 2);

    prep_kernel<<<36, 256, 0, stream>>>(W1, W1T, counts, g1 + (size_t)n * DIM, n);
    long long nchunk = ((long long)e + 256 * EPC - 1) / (256 * EPC);
    count_ell_kernel<<<(unsigned)(nchunk * 8), 256, 0, stream>>>(ei, counts, col_ell, spill, n, e);
    gemm1_kernel<<<(n + GR - 1) / GR, 256, 0, stream>>>(x, W1T, counts, g1, n);

    int B = n >> 7, r = n & 127;
    int nclsmax = B * 16 + (r < 16 ? r : 16);
    int agg1_blocks = 8 * ((nclsmax + 3) / 4);
    int agg2_blocks = 8 * ((nclsmax + 15) / 16);
    agg1_kernel<<<agg1_blocks, 256, 0, stream>>>(g1, counts, col_ell, spill, b1, W2, g2, n);
    agg2_kernel<<<agg2_blocks, 256, 0, stream>>>(g2, counts, col_ell, spill, b2, out, n);
}